// Round 11
// baseline (1997.958 us; speedup 1.0000x reference)
//
#include <hip/hip_runtime.h>
#include <math.h>

#define N_NODES 131072
#define N_EDGES 2097152
#define S_SEG   512
#define F_INPUT 64
#define HID     128
#define EMB     128
#define RNN_HID 256

// ---------------------------------------------------------------------------
// Graph preprocessing: counts + weighted degree
// ---------------------------------------------------------------------------
__global__ void zero_kernel(int* __restrict__ cnt, float* __restrict__ degw, int n) {
    int i = blockIdx.x * blockDim.x + threadIdx.x;
    if (i < n) { cnt[i] = 0; degw[i] = 0.f; }
}

__global__ void count_kernel(const int* __restrict__ dst, const float* __restrict__ ew,
                             int* __restrict__ cnt, float* __restrict__ degw, int e) {
    int i = blockIdx.x * blockDim.x + threadIdx.x;
    if (i < e) {
        int d = dst[i];
        atomicAdd(&cnt[d], 1);
        atomicAdd(&degw[d], ew[i]);
    }
}

// exclusive scan of cnt[n] -> row_ptr[n+1]; cnt becomes cursor (copy of row_ptr)
__global__ __launch_bounds__(1024) void scan_kernel(int* __restrict__ cnt,
                                                    int* __restrict__ row_ptr, int n) {
    __shared__ int sums[1024];
    int tid = threadIdx.x;
    int per = n / 1024;            // 128
    int base = tid * per;
    int s = 0;
    for (int k = 0; k < per; k++) s += cnt[base + k];
    sums[tid] = s;
    __syncthreads();
    for (int off = 1; off < 1024; off <<= 1) {
        int v = (tid >= off) ? sums[tid - off] : 0;
        __syncthreads();
        sums[tid] += v;
        __syncthreads();
    }
    int run = (tid > 0) ? sums[tid - 1] : 0;
    for (int k = 0; k < per; k++) {
        int v = cnt[base + k];
        row_ptr[base + k] = run;
        cnt[base + k] = run;       // cursor
        run += v;
    }
    if (tid == 1023) row_ptr[n] = run;
}

__global__ void dinv_kernel(const float* __restrict__ degw, float* __restrict__ dinv, int n) {
    int i = blockIdx.x * blockDim.x + threadIdx.x;
    if (i < n) dinv[i] = rsqrtf(degw[i] + 1.0f);   // +1 = self-loop weight
}

// scatter edges into CSR; fold the FULL symmetric norm into the stored value:
// wv[p] = dinv[dst] * ew * dinv[src]  (graph-only -> computed once, reused 3x)
__global__ void scatter_kernel(const int* __restrict__ src, const int* __restrict__ dst,
                               const float* __restrict__ ew, int* __restrict__ cursor,
                               const float* __restrict__ dinv,
                               int* __restrict__ col, float* __restrict__ wv, int e) {
    int i = blockIdx.x * blockDim.x + threadIdx.x;
    if (i < e) {
        int d = dst[i];
        int s = src[i];
        int p = atomicAdd(&cursor[d], 1);
        col[p] = s;
        wv[p]  = dinv[d] * ew[i] * dinv[s];
    }
}

// ---------------------------------------------------------------------------
// Dense GEMM: Y[M x 128] = X[M x K] @ W[K x 128], K in {64,128}, M % 64 == 0
// Staging remap (round-10 fix): lane = row, kq uniform per wave -> LDS
// transpose-writes are stride-1 (2 lanes/bank = free). Was 8-way conflict
// (3.67M conflict cycles, stride 4*68 = 16 mod 32).
// ---------------------------------------------------------------------------
__global__ __launch_bounds__(256) void gemm_kernel(const float* __restrict__ X,
                                                   const float* __restrict__ W,
                                                   float* __restrict__ Y, int K) {
    __shared__ float Xs[64][68];   // [k][m], padded
    __shared__ float Ws[64][128];  // [k][n]
    int tid = threadIdx.x;
    int m0 = blockIdx.x * 64;
    int tr = tid >> 5;             // 0..7
    int tc = tid & 31;             // 0..31
    int r0 = tr * 8;
    int c0 = tc * 4;
    float acc[8][4];
#pragma unroll
    for (int i = 0; i < 8; i++)
#pragma unroll
        for (int j = 0; j < 4; j++) acc[i][j] = 0.f;

    for (int kt = 0; kt < K; kt += 64) {
        // stage X tile (64 rows x 64 k) transposed into Xs[k][m].
        // row = lin&63 (=lane), kq = lin>>6 (uniform per wave) ->
        // each scalar store hits addresses const+lane: conflict-free.
#pragma unroll
        for (int i = 0; i < 4; i++) {
            int lin = i * 256 + tid;
            int row = lin & 63;
            int kq  = lin >> 6;
            float4 v = *(const float4*)&X[(size_t)(m0 + row) * K + kt + kq * 4];
            Xs[kq * 4 + 0][row] = v.x;
            Xs[kq * 4 + 1][row] = v.y;
            Xs[kq * 4 + 2][row] = v.z;
            Xs[kq * 4 + 3][row] = v.w;
        }
#pragma unroll
        for (int i = 0; i < 8; i++) {
            int lin = i * 256 + tid;
            int kk = lin >> 5;
            int cq = lin & 31;
            *(float4*)&Ws[kk][cq * 4] = *(const float4*)&W[(size_t)(kt + kk) * 128 + cq * 4];
        }
        __syncthreads();
#pragma unroll
        for (int k = 0; k < 64; k++) {
            float4 b  = *(const float4*)&Ws[k][c0];
            float4 a0 = *(const float4*)&Xs[k][r0];
            float4 a1 = *(const float4*)&Xs[k][r0 + 4];
            float a[8] = {a0.x, a0.y, a0.z, a0.w, a1.x, a1.y, a1.z, a1.w};
            float bb[4] = {b.x, b.y, b.z, b.w};
#pragma unroll
            for (int i = 0; i < 8; i++)
#pragma unroll
                for (int j = 0; j < 4; j++) acc[i][j] += a[i] * bb[j];
        }
        __syncthreads();
    }
#pragma unroll
    for (int i = 0; i < 8; i++) {
        float4 v = make_float4(acc[i][0], acc[i][1], acc[i][2], acc[i][3]);
        *(float4*)&Y[(size_t)(m0 + r0 + i) * 128 + c0] = v;
    }
}

// ---------------------------------------------------------------------------
// SpMM: out[i][:] = relu( dinv[i]^2*t[i][:] + sum_p wv[p]*t[col[p]][:] + b )
// ---------------------------------------------------------------------------
__global__ __launch_bounds__(256) void spmm_kernel(const float* __restrict__ t,
                                                   const int* __restrict__ row_ptr,
                                                   const int* __restrict__ col,
                                                   const float* __restrict__ wv,
                                                   const float* __restrict__ dinv,
                                                   const float* __restrict__ bias,
                                                   float* __restrict__ out) {
    int wave = threadIdx.x >> 6;
    int lane = threadIdx.x & 63;
    int i = blockIdx.x * 4 + wave;
    int f = lane * 2;
    float di = dinv[i];
    float2 self = *(const float2*)&t[(size_t)i * HID + f];
    float sc = di * di;
    float ax = sc * self.x, ay = sc * self.y;
    int p0 = row_ptr[i], p1 = row_ptr[i + 1];
    int p = p0;
    for (; p + 4 <= p1; p += 4) {
        int c0 = col[p];
        int c1 = col[p + 1];
        int c2 = col[p + 2];
        int c3 = col[p + 3];
        float w0 = wv[p];
        float w1 = wv[p + 1];
        float w2 = wv[p + 2];
        float w3 = wv[p + 3];
        float2 v0 = *(const float2*)&t[(size_t)c0 * HID + f];
        float2 v1 = *(const float2*)&t[(size_t)c1 * HID + f];
        float2 v2 = *(const float2*)&t[(size_t)c2 * HID + f];
        float2 v3 = *(const float2*)&t[(size_t)c3 * HID + f];
        ax += w0 * v0.x + w1 * v1.x + w2 * v2.x + w3 * v3.x;
        ay += w0 * v0.y + w1 * v1.y + w2 * v2.y + w3 * v3.y;
    }
    for (; p < p1; p++) {
        int c = col[p];
        float coef = wv[p];
        float2 v = *(const float2*)&t[(size_t)c * HID + f];
        ax += coef * v.x;
        ay += coef * v.y;
    }
    float2 b = *(const float2*)&bias[f];
    ax = fmaxf(ax + b.x, 0.f);
    ay = fmaxf(ay + b.y, 0.f);
    float2 r; r.x = ax; r.y = ay;
    *(float2*)&out[(size_t)i * HID + f] = r;
}

// ---------------------------------------------------------------------------
// Segment starts via binary search on sorted batch
// ---------------------------------------------------------------------------
__global__ void segstart_kernel(const int* __restrict__ batch, int* __restrict__ seg, int n) {
    int s = blockIdx.x * blockDim.x + threadIdx.x;
    if (s <= S_SEG) {
        int lo = 0, hi = n;
        while (lo < hi) {
            int m = (lo + hi) >> 1;
            if (batch[m] < s) lo = m + 1; else hi = m;
        }
        seg[s] = lo;
    }
}

__global__ __launch_bounds__(128) void pool_kernel(const float* __restrict__ z,
                                                   const int* __restrict__ seg,
                                                   float* __restrict__ pooled) {
    int s = blockIdx.x;
    int fidx = threadIdx.x;
    int a = seg[s], b = seg[s + 1];
    float sum = 0.f;
    for (int r = a; r < b; r++) sum += z[(size_t)r * HID + fidx];
    float cnt = (float)(b - a);
    pooled[(size_t)s * EMB + fidx] = sum / fmaxf(cnt, 1.f);
}

// ---------------------------------------------------------------------------
// Precompute U[t][j] = pooled[t] . Wih[j] + bih[j] + bhh[j]
// ---------------------------------------------------------------------------
__global__ __launch_bounds__(256) void ucomp_kernel(const float* __restrict__ pooled,
                                                    const float* __restrict__ Wih,
                                                    const float* __restrict__ bih,
                                                    const float* __restrict__ bhh,
                                                    float* __restrict__ U) {
    __shared__ float xs[EMB];
    int t = blockIdx.x;
    int j = threadIdx.x;
    if (j < EMB) xs[j] = pooled[(size_t)t * EMB + j];
    __syncthreads();
    const float* wr = Wih + (size_t)j * EMB;
    float a0 = 0.f, a1 = 0.f, a2 = 0.f, a3 = 0.f;
#pragma unroll
    for (int k = 0; k < EMB; k += 16) {
        float4 w0 = *(const float4*)&wr[k];
        float4 w1 = *(const float4*)&wr[k + 4];
        float4 w2 = *(const float4*)&wr[k + 8];
        float4 w3 = *(const float4*)&wr[k + 12];
        a0 += w0.x * xs[k]      + w0.y * xs[k + 1]  + w0.z * xs[k + 2]  + w0.w * xs[k + 3];
        a1 += w1.x * xs[k + 4]  + w1.y * xs[k + 5]  + w1.z * xs[k + 6]  + w1.w * xs[k + 7];
        a2 += w2.x * xs[k + 8]  + w2.y * xs[k + 9]  + w2.z * xs[k + 10] + w2.w * xs[k + 11];
        a3 += w3.x * xs[k + 12] + w3.y * xs[k + 13] + w3.z * xs[k + 14] + w3.w * xs[k + 15];
    }
    U[(size_t)t * RNN_HID + j] = ((a0 + a1) + (a2 + a3)) + bih[j] + bhh[j];
}

// ---------------------------------------------------------------------------
// Serial tanh RNN: h_t = tanh(U[t] + Whh @ h_{t-1})
// 512 threads (8 waves, 2/SIMD). Thread (jg = tid>>3, q = tid&7) owns 4
// outputs over k-slice [32q, 32q+32).
// Round-10 lesson (VGPR_Count=84): a float4 w[4][8] ARRAY exceeds the
// promote-alloca threshold -> scratch -> 256KB/step reload = streaming-bound.
// Fix: 32 individually NAMED float4 SSA values -> register allocator must
// keep them live (128 VGPR + ~50 working < 256 cap at waves_per_eu=2).
// LDS rotation f = q*8+((c+q)&7): 8 distinct q-addresses partition all 32
// banks, broadcast within q -> 0 conflicts (verified round 9/10).
// ---------------------------------------------------------------------------
#define FIDX(c) ((q * 8 + (((c) + q) & 7)) * 4)
__global__ __launch_bounds__(512, 2) void rnn_kernel(const float* __restrict__ U,
                                                     const float* __restrict__ Whh,
                                                     float* __restrict__ hs) {
    __shared__ float hb[2][RNN_HID];
    int tid = threadIdx.x;
    int jg = tid >> 3;         // output-group 0..63 (outputs 4jg..4jg+3)
    int q  = tid & 7;          // k-slice 0..7 (k in [32q, 32q+32))

    const float* w0r = Whh + (size_t)(jg * 4 + 0) * RNN_HID;
    const float* w1r = Whh + (size_t)(jg * 4 + 1) * RNN_HID;
    const float* w2r = Whh + (size_t)(jg * 4 + 2) * RNN_HID;
    const float* w3r = Whh + (size_t)(jg * 4 + 3) * RNN_HID;
    const float4 w00 = *(const float4*)&w0r[FIDX(0)], w01 = *(const float4*)&w0r[FIDX(1)],
                 w02 = *(const float4*)&w0r[FIDX(2)], w03 = *(const float4*)&w0r[FIDX(3)],
                 w04 = *(const float4*)&w0r[FIDX(4)], w05 = *(const float4*)&w0r[FIDX(5)],
                 w06 = *(const float4*)&w0r[FIDX(6)], w07 = *(const float4*)&w0r[FIDX(7)];
    const float4 w10 = *(const float4*)&w1r[FIDX(0)], w11 = *(const float4*)&w1r[FIDX(1)],
                 w12 = *(const float4*)&w1r[FIDX(2)], w13 = *(const float4*)&w1r[FIDX(3)],
                 w14 = *(const float4*)&w1r[FIDX(4)], w15 = *(const float4*)&w1r[FIDX(5)],
                 w16 = *(const float4*)&w1r[FIDX(6)], w17 = *(const float4*)&w1r[FIDX(7)];
    const float4 w20 = *(const float4*)&w2r[FIDX(0)], w21 = *(const float4*)&w2r[FIDX(1)],
                 w22 = *(const float4*)&w2r[FIDX(2)], w23 = *(const float4*)&w2r[FIDX(3)],
                 w24 = *(const float4*)&w2r[FIDX(4)], w25 = *(const float4*)&w2r[FIDX(5)],
                 w26 = *(const float4*)&w2r[FIDX(6)], w27 = *(const float4*)&w2r[FIDX(7)];
    const float4 w30 = *(const float4*)&w3r[FIDX(0)], w31 = *(const float4*)&w3r[FIDX(1)],
                 w32 = *(const float4*)&w3r[FIDX(2)], w33 = *(const float4*)&w3r[FIDX(3)],
                 w34 = *(const float4*)&w3r[FIDX(4)], w35 = *(const float4*)&w3r[FIDX(5)],
                 w36 = *(const float4*)&w3r[FIDX(6)], w37 = *(const float4*)&w3r[FIDX(7)];

    if (tid < RNN_HID) hb[0][tid] = 0.f;
    __syncthreads();

    int j_out = jg * 4 + (q & 3);      // output this thread finalizes (q<4 writes)
    float u_next = U[j_out];           // t = 0
    int p = 0;
    for (int t = 0; t < S_SEG; t++) {
        float u = u_next;
        if (t + 1 < S_SEG) u_next = U[(size_t)(t + 1) * RNN_HID + j_out];

        float a0 = 0.f, a1 = 0.f, a2 = 0.f, a3 = 0.f;
#define RSTEP(c, W0, W1, W2, W3) { \
        float4 h4 = *(const float4*)&hb[p][FIDX(c)]; \
        a0 += W0.x * h4.x + W0.y * h4.y + W0.z * h4.z + W0.w * h4.w; \
        a1 += W1.x * h4.x + W1.y * h4.y + W1.z * h4.z + W1.w * h4.w; \
        a2 += W2.x * h4.x + W2.y * h4.y + W2.z * h4.z + W2.w * h4.w; \
        a3 += W3.x * h4.x + W3.y * h4.y + W3.z * h4.z + W3.w * h4.w; }
        RSTEP(0, w00, w10, w20, w30)
        RSTEP(1, w01, w11, w21, w31)
        RSTEP(2, w02, w12, w22, w32)
        RSTEP(3, w03, w13, w23, w33)
        RSTEP(4, w04, w14, w24, w34)
        RSTEP(5, w05, w15, w25, w35)
        RSTEP(6, w06, w16, w26, w36)
        RSTEP(7, w07, w17, w27, w37)
#undef RSTEP
        // reduce each acc across the 8-lane k-group (lanes 8jg..8jg+7)
        a0 += __shfl_xor(a0, 1, 64); a0 += __shfl_xor(a0, 2, 64); a0 += __shfl_xor(a0, 4, 64);
        a1 += __shfl_xor(a1, 1, 64); a1 += __shfl_xor(a1, 2, 64); a1 += __shfl_xor(a1, 4, 64);
        a2 += __shfl_xor(a2, 1, 64); a2 += __shfl_xor(a2, 2, 64); a2 += __shfl_xor(a2, 4, 64);
        a3 += __shfl_xor(a3, 1, 64); a3 += __shfl_xor(a3, 2, 64); a3 += __shfl_xor(a3, 4, 64);
        // branch-free select: lane q takes acc[q&3]
        float s0 = (q & 1) ? a1 : a0;
        float s1 = (q & 1) ? a3 : a2;
        float acc = (q & 2) ? s1 : s0;

        float hn = tanhf(acc + u);
        if (q < 4) {
            hb[p ^ 1][j_out] = hn;
            hs[(size_t)t * RNN_HID + j_out] = hn;
        }
        __syncthreads();
        p ^= 1;
    }
}
#undef FIDX

// ---------------------------------------------------------------------------
// Final linear + sigmoid: one wave per sequence position
// ---------------------------------------------------------------------------
__global__ __launch_bounds__(256) void logits_kernel(const float* __restrict__ hs,
                                                     const float* __restrict__ Wl,
                                                     const float* __restrict__ bl,
                                                     float* __restrict__ out) {
    int tid = threadIdx.x;
    int wave = tid >> 6, lane = tid & 63;
    int s = blockIdx.x * 4 + wave;
    float4 h = ((const float4*)&hs[(size_t)s * RNN_HID])[lane];
    float4 w0 = ((const float4*)Wl)[lane];
    float4 w1 = ((const float4*)(Wl + RNN_HID))[lane];
    float a0 = h.x * w0.x + h.y * w0.y + h.z * w0.z + h.w * w0.w;
    float a1 = h.x * w1.x + h.y * w1.y + h.z * w1.z + h.w * w1.w;
#pragma unroll
    for (int off = 32; off; off >>= 1) {
        a0 += __shfl_xor(a0, off, 64);
        a1 += __shfl_xor(a1, off, 64);
    }
    if (lane == 0) {
        out[s * 2 + 0] = 1.f / (1.f + expf(-(a0 + bl[0])));
        out[s * 2 + 1] = 1.f / (1.f + expf(-(a1 + bl[1])));
    }
}

// ---------------------------------------------------------------------------
extern "C" void kernel_launch(void* const* d_in, const int* in_sizes, int n_in,
                              void* d_out, int out_size, void* d_ws, size_t ws_size,
                              hipStream_t stream) {
    const float* x    = (const float*)d_in[0];
    const float* ew   = (const float*)d_in[1];
    const int*   src  = (const int*)d_in[2];
    const int*   dst  = (const int*)d_in[3];
    const int*   batch= (const int*)d_in[4];
    const float* W1   = (const float*)d_in[5];
    const float* b1   = (const float*)d_in[6];
    const float* W2   = (const float*)d_in[7];
    const float* b2   = (const float*)d_in[8];
    const float* W3   = (const float*)d_in[9];
    const float* b3   = (const float*)d_in[10];
    const float* Wih  = (const float*)d_in[11];
    const float* Whh  = (const float*)d_in[12];
    const float* bih  = (const float*)d_in[13];
    const float* bhh  = (const float*)d_in[14];
    const float* Wl   = (const float*)d_in[15];
    const float* bl   = (const float*)d_in[16];
    float* out = (float*)d_out;
    (void)in_sizes; (void)n_in; (void)out_size; (void)ws_size;

    char* ws = (char*)d_ws;
    size_t o = 0;
    auto alloc = [&](size_t bytes) -> char* {
        o = (o + 255) & ~(size_t)255;
        char* p = ws + o;
        o += bytes;
        return p;
    };
    float* bufA   = (float*)alloc((size_t)N_NODES * HID * 4);
    float* bufB   = (float*)alloc((size_t)N_NODES * HID * 4);
    int*   colA   = (int*)  alloc((size_t)N_EDGES * 4);
    float* wvA    = (float*)alloc((size_t)N_EDGES * 4);
    int*   rowp   = (int*)  alloc((size_t)(N_NODES + 1) * 4);
    int*   cursor = (int*)  alloc((size_t)N_NODES * 4);
    float* degw   = (float*)alloc((size_t)N_NODES * 4);
    float* dinv   = (float*)alloc((size_t)N_NODES * 4);
    int*   seg    = (int*)  alloc((size_t)(S_SEG + 1) * 4);
    float* pooled = (float*)alloc((size_t)S_SEG * EMB * 4);
    float* hs     = (float*)alloc((size_t)S_SEG * RNN_HID * 4);
    float* U      = (float*)alloc((size_t)S_SEG * RNN_HID * 4);

    // --- CSR build (edge norms folded in once, reused by all 3 layers) ---
    zero_kernel<<<(N_NODES + 255) / 256, 256, 0, stream>>>(cursor, degw, N_NODES);
    count_kernel<<<(N_EDGES + 255) / 256, 256, 0, stream>>>(dst, ew, cursor, degw, N_EDGES);
    scan_kernel<<<1, 1024, 0, stream>>>(cursor, rowp, N_NODES);
    dinv_kernel<<<(N_NODES + 255) / 256, 256, 0, stream>>>(degw, dinv, N_NODES);
    scatter_kernel<<<(N_EDGES + 255) / 256, 256, 0, stream>>>(src, dst, ew, cursor, dinv, colA, wvA, N_EDGES);

    // --- GCN layers ---
    gemm_kernel<<<N_NODES / 64, 256, 0, stream>>>(x, W1, bufA, F_INPUT);
    spmm_kernel<<<N_NODES / 4, 256, 0, stream>>>(bufA, rowp, colA, wvA, dinv, b1, bufB);
    gemm_kernel<<<N_NODES / 64, 256, 0, stream>>>(bufB, W2, bufA, HID);
    spmm_kernel<<<N_NODES / 4, 256, 0, stream>>>(bufA, rowp, colA, wvA, dinv, b2, bufB);
    gemm_kernel<<<N_NODES / 64, 256, 0, stream>>>(bufB, W3, bufA, HID);
    spmm_kernel<<<N_NODES / 4, 256, 0, stream>>>(bufA, rowp, colA, wvA, dinv, b3, bufB);

    // --- mean pool per subgraph ---
    segstart_kernel<<<(S_SEG + 1 + 255) / 256, 256, 0, stream>>>(batch, seg, N_NODES);
    pool_kernel<<<S_SEG, 128, 0, stream>>>(bufB, seg, pooled);

    // --- RNN: hoisted input projection, then serial loop ---
    ucomp_kernel<<<S_SEG, 256, 0, stream>>>(pooled, Wih, bih, bhh, U);
    rnn_kernel<<<1, 512, 0, stream>>>(U, Whh, hs);
    logits_kernel<<<S_SEG / 4, 256, 0, stream>>>(hs, Wl, bl, out);
}